// Round 17
// baseline (246.148 us; speedup 1.0000x reference)
//
#include <hip/hip_runtime.h>
#include <hip/hip_bf16.h>

#define LSDIM 30

typedef __attribute__((ext_vector_type(8))) short short8;
typedef __attribute__((ext_vector_type(4))) short s16x4;
typedef __attribute__((ext_vector_type(4))) float f32x4;

__device__ __forceinline__ float lrelu(float v) { return v >= 0.0f ? v : 0.01f * v; }

// ---------------- Fused encoder: conv1..conv4 + FC + reparam (unchanged) ----------------
__global__ __launch_bounds__(256) void encoder_kernel(
    const float* __restrict__ x, const float* __restrict__ eps,
    const float* __restrict__ w1, const float* __restrict__ b1,
    const float* __restrict__ w2, const float* __restrict__ b2,
    const float* __restrict__ w3, const float* __restrict__ b3,
    const float* __restrict__ w4, const float* __restrict__ b4,
    const float* __restrict__ mw, const float* __restrict__ mb,
    const float* __restrict__ vw, const float* __restrict__ vb,
    float* __restrict__ out_mu, float* __restrict__ out_lv, float* __restrict__ out_z,
    float* __restrict__ ws_z)
{
  __shared__ float xs[784];
  __shared__ float h1[8 * 169];
  __shared__ float h2[16 * 36];
  __shared__ float h3[32 * 16];
  __shared__ float flat[256];
  __shared__ float mlv[60];

  const int b = blockIdx.x;
  const int tid = threadIdx.x;

  const float* xb = x + b * 784;
  for (int i = tid; i < 784; i += 256) xs[i] = xb[i];
  __syncthreads();

  for (int idx = tid; idx < 8 * 169; idx += 256) {
    int c = idx / 169, r = idx % 169;
    int py = r / 13, px = r % 13;
    float wv[9];
#pragma unroll
    for (int t = 0; t < 9; ++t) wv[t] = w1[c * 9 + t];
    float bias = b1[c];
    float m = -1e30f;
#pragma unroll
    for (int dy = 0; dy < 2; ++dy)
#pragma unroll
      for (int dx = 0; dx < 2; ++dx) {
        int oy = 2 * py + dy, ox = 2 * px + dx;
        float acc = bias;
#pragma unroll
        for (int ky = 0; ky < 3; ++ky)
#pragma unroll
          for (int kx = 0; kx < 3; ++kx)
            acc = fmaf(wv[ky * 3 + kx], xs[(oy + ky) * 28 + ox + kx], acc);
        m = fmaxf(m, lrelu(acc));
      }
    h1[idx] = m;
  }
  __syncthreads();

  for (int idx = tid; idx < 16 * 36; idx += 256) {
    int c = idx / 36, r = idx % 36;
    int py = r / 6, px = r % 6;
    float bias = b2[c];
    float m = -1e30f;
#pragma unroll
    for (int dy = 0; dy < 2; ++dy)
#pragma unroll
      for (int dx = 0; dx < 2; ++dx) {
        int oy = 2 * py + dy, ox = 2 * px + dx;
        float acc = bias;
        for (int ic = 0; ic < 8; ++ic) {
#pragma unroll
          for (int ky = 0; ky < 2; ++ky)
#pragma unroll
            for (int kx = 0; kx < 2; ++kx)
              acc = fmaf(w2[((c * 8 + ic) * 2 + ky) * 2 + kx],
                         h1[ic * 169 + (oy + ky) * 13 + ox + kx], acc);
        }
        m = fmaxf(m, lrelu(acc));
      }
    h2[idx] = m;
  }
  __syncthreads();

  for (int idx = tid; idx < 32 * 16; idx += 256) {
    int c = idx / 16, r = idx % 16;
    int y = r / 4, xq = r % 4;
    float acc = b3[c];
    for (int ic = 0; ic < 16; ++ic) {
#pragma unroll
      for (int ky = 0; ky < 3; ++ky)
#pragma unroll
        for (int kx = 0; kx < 3; ++kx)
          acc = fmaf(w3[((c * 16 + ic) * 3 + ky) * 3 + kx],
                     h2[ic * 36 + (y + ky) * 6 + xq + kx], acc);
    }
    h3[idx] = lrelu(acc);
  }
  __syncthreads();

  {
    int c = tid >> 2, r = tid & 3;
    int y = r >> 1, xq = r & 1;
    float acc = b4[c];
    for (int ic = 0; ic < 32; ++ic) {
#pragma unroll
      for (int ky = 0; ky < 3; ++ky)
#pragma unroll
        for (int kx = 0; kx < 3; ++kx)
          acc = fmaf(w4[((c * 32 + ic) * 3 + ky) * 3 + kx],
                     h3[ic * 16 + (y + ky) * 4 + xq + kx], acc);
    }
    flat[tid] = lrelu(acc);
  }
  __syncthreads();

  if (tid < 60) {
    int j = tid < 30 ? tid : tid - 30;
    const float* W = tid < 30 ? mw : vw;
    float acc = (tid < 30 ? mb[j] : vb[j]);
    for (int k = 0; k < 256; ++k) acc = fmaf(W[j * 256 + k], flat[k], acc);
    mlv[tid] = acc;
  }
  __syncthreads();

  if (tid < LSDIM) {
    float mu = mlv[tid], lv = mlv[30 + tid];
    float z = fmaf(eps[b * LSDIM + tid], expf(0.5f * lv), mu);
    out_mu[b * LSDIM + tid] = mu;
    out_lv[b * LSDIM + tid] = lv;
    out_z[b * LSDIM + tid] = z;
    ws_z[b * LSDIM + tid] = z;
  }
}

// ---------------- Weight repack (unchanged layout) ----------------
// wb[((nt*nks + ks)*64 + l)*8 + e] = W[k][n], k = ks*32 + ((l>>4)&3)*8 + e,
// n = nt*16 + (l&15), k = (dy*3+dx)*CIN + ic  (ks = dy*QK + q)
__global__ __launch_bounds__(256) void repack_all(
    const float* __restrict__ w5, const float* __restrict__ w6,
    const float* __restrict__ w7, const float* __restrict__ w8,
    __hip_bfloat16* __restrict__ wb5, __hip_bfloat16* __restrict__ wb6,
    __hip_bfloat16* __restrict__ wb7, __hip_bfloat16* __restrict__ wb8)
{
  int i = blockIdx.x * 256 + threadIdx.x;
  const float* w;
  __hip_bfloat16* wb;
  int CIN, nks, j;
  if (i < 18432)       { w = w5; wb = wb5; CIN = 32; nks = 9;  j = i; }
  else if (i < 55296)  { w = w6; wb = wb6; CIN = 64; nks = 18; j = i - 18432; }
  else if (i < 92160)  { w = w7; wb = wb7; CIN = 64; nks = 18; j = i - 55296; }
  else if (i < 129024) { w = w8; wb = wb8; CIN = 64; nks = 18; j = i - 92160; }
  else return;
  int e = j & 7, l = (j >> 3) & 63;
  int ksnt = j >> 9;
  int ks = ksnt % nks, nt = ksnt / nks;
  int k = ks * 32 + ((l >> 4) & 3) * 8 + e;
  int n = nt * 16 + (l & 15);
  int d = k / CIN, ic = k % CIN;
  int dy = d / 3, dx = d % 3;
  wb[j] = __float2bfloat16(w[((n * CIN + ic) * 3 + dy) * 3 + dx]);
}

// ---------------- One conv phase: 16 waves, 7-row slab, swapped operands,
//                  wave-staggered q order ----------------
// Static layout: row y at slot y+1; slots 0/29 permanent zero halos.
// addr = slot*4096 + j*128 + c*2, XOR ^= (j&7)<<4.
// 16 waves = 4 slabs (7 rows) x 2 nh (32-ch halves) x 2 mt (16-col halves).
// q SEQUENTIAL (#pragma unroll 1): back-edge bounds B-load hoisting (full
// unroll spills, R3-R9; ANY register prefetch spills, R15 -- arch budget
// pinned at 64: Bq 24 + A 8 + bias/addr ~30 fills it).
// STAGGER: wave wv starts at q = wv % QK, wrapping -- de-correlates the
// per-q B-load (vmcnt) and first-A (lgkmcnt) stalls across the 4 waves of a
// SIMD so TLP fills the bubbles (accumulation order change is fp-benign).
// mfma(W, X, acc): swap transposes D -> lane holds 4 consecutive channels
// at one column -> b64 epilogue (R14: 250->207us).
template <int CIN, bool FUSE9>
__device__ __forceinline__ void conv_phase(
    char* __restrict__ smem, float* __restrict__ red, int b,
    const short8* __restrict__ wbp, const float* __restrict__ bias,
    const float* __restrict__ w9, const float* __restrict__ b9,
    float* __restrict__ dout)
{
  constexpr int NKS = CIN * 9 / 32;   // 9 or 18
  constexpr int QK  = NKS / 3;        // per-dy k-steps: 3 or 6

  const int tid = threadIdx.x;
  const int lane = tid & 63, wv = tid >> 6;     // wv 0..15
  const int slab = wv >> 2;                     // 0..3
  const int nh   = (wv >> 1) & 1;               // channel half
  const int mt   = wv & 1;                      // column half
  const int lg = (lane >> 4) & 3, ml = lane & 15;

  // per-lane bias vectors: 4 consecutive channels per tt
  f32x4 bbv[2];
#pragma unroll
  for (int tt = 0; tt < 2; ++tt)
    bbv[tt] = *(const f32x4*)(bias + (2 * nh + tt) * 16 + lg * 4);

  f32x4 acc[7][2];   // [o][tt]; lane holds channels n0..n0+3 at col xx
#pragma unroll
  for (int o = 0; o < 7; ++o)
#pragma unroll
    for (int nt = 0; nt < 2; ++nt) {
      f32x4 z = {0.f, 0.f, 0.f, 0.f};
      acc[o][nt] = z;
    }

  const int qs = wv % QK;   // wave-static q stagger (uniform, SALU)

  __syncthreads();   // previous phase's writes (or synth) visible

#pragma unroll 1     // REAL loop: bounds B-load hoisting to ~1 iteration
  for (int qi = 0; qi < QK; ++qi) {
    int q = qi + qs; if (q >= QK) q -= QK;

    short8 Bq[3][2];  // weight fragments: 3 dy x 2 nt = 24 VGPRs
#pragma unroll
    for (int dy = 0; dy < 3; ++dy)
#pragma unroll
      for (int nt = 0; nt < 2; ++nt)
        Bq[dy][nt] = wbp[((2 * nh + nt) * NKS + dy * QK + q) * 64 + lane];

    const int dx  = (CIN == 64) ? (q >> 1) : q;
    const int ic0 = ((CIN == 64) ? ((q & 1) * 32) : 0) + lg * 8;
    const int j   = (mt * 16 + ml + dx) & 31;   // wrapped lanes feed x>=28 (discarded)
    const int off = (j * 128 + ic0 * 2) ^ ((j & 7) << 4);

    __builtin_amdgcn_s_setprio(1);
#pragma unroll
    for (int r = 0; r < 9; ++r) {    // input rows 7*slab-1 .. 7*slab+7
      short8 A = *(const short8*)(smem + (7 * slab + r) * 4096 + off);
#pragma unroll
      for (int dy = 0; dy < 3; ++dy) {
        const int o = r - dy;        // output row within slab
        if (o < 0 || o > 6) continue;
        // SWAPPED: weights in A-slot, acts in B-slot
        acc[o][0] = __builtin_amdgcn_mfma_f32_16x16x32_bf16(Bq[dy][0], A, acc[o][0], 0, 0, 0);
        acc[o][1] = __builtin_amdgcn_mfma_f32_16x16x32_bf16(Bq[dy][1], A, acc[o][1], 0, 0, 0);
      }
    }
    __builtin_amdgcn_s_setprio(0);
  }

  __syncthreads();   // ALL reads of this conv done -> in-place writes safe

  const int xx = mt * 16 + ml;   // this lane's output column (fixed)

  if constexpr (!FUSE9) {
    if (xx < 28) {
      const int j = xx + 1;
#pragma unroll
      for (int o = 0; o < 7; ++o) {
        const int wslot = 7 * slab + o + 1;
#pragma unroll
        for (int tt = 0; tt < 2; ++tt) {
          const int n0 = (2 * nh + tt) * 16 + lg * 4;
          s16x4 pk;
#pragma unroll
          for (int reg = 0; reg < 4; ++reg) {
            __hip_bfloat16 h = __float2bfloat16(lrelu(acc[o][tt][reg] + bbv[tt][reg]));
            pk[reg] = __builtin_bit_cast(short, h);
          }
          int addr = wslot * 4096 + j * 128 + n0 * 2;
          addr ^= (j & 7) << 4;
          *(s16x4*)(smem + addr) = pk;   // 8B: 4 consecutive channels
        }
      }
    }
    // re-zero x-pad cols 0 and 29 of written rows (b64 chunks, ml 0/1 lanes)
    if (mt == 0 && ml < 2) {
      const int j = ml ? 29 : 0;
      s16x4 z4 = {0, 0, 0, 0};
#pragma unroll
      for (int o = 0; o < 7; ++o) {
        const int wslot = 7 * slab + o + 1;
#pragma unroll
        for (int tt = 0; tt < 2; ++tt) {
          const int n0 = (2 * nh + tt) * 16 + lg * 4;
          int addr = wslot * 4096 + j * 128 + n0 * 2;
          addr ^= (j & 7) << 4;
          *(s16x4*)(smem + addr) = z4;
        }
      }
    }
    // next phase's opening barrier orders these writes before its reads
  } else {
    // conv9 (1x1, 64->1): lane holds 8 channels (2tt x 4reg) at col xx;
    // in-lane dot, then reduce across lg groups (shfl 16, 32) = 32-ch sum.
    f32x4 w9v[2];
#pragma unroll
    for (int tt = 0; tt < 2; ++tt)
      w9v[tt] = *(const f32x4*)(w9 + (2 * nh + tt) * 16 + lg * 4);
    const float b9v = b9[0];
#pragma unroll
    for (int o = 0; o < 7; ++o) {
      float p = 0.0f;
#pragma unroll
      for (int tt = 0; tt < 2; ++tt)
#pragma unroll
        for (int reg = 0; reg < 4; ++reg)
          p = fmaf(w9v[tt][reg], lrelu(acc[o][tt][reg] + bbv[tt][reg]), p);
      p += __shfl_xor(p, 16);
      p += __shfl_xor(p, 32);
      if (lg == 0 && xx < 28) {
        const int y = 7 * slab + o;
        red[(y * 32 + xx) * 2 + nh] = p;
      }
    }
    __syncthreads();
    for (int idx = tid; idx < 784; idx += 1024) {
      const int y = idx / 28, xc = idx % 28;
      float o9 = lrelu(b9v + red[(y * 32 + xc) * 2] + red[(y * 32 + xc) * 2 + 1]);
      dout[b * 784 + y * 28 + xc] = o9;
    }
  }
}

// ---------------- Fused decoder: synth + conv5..conv8 + conv9, all in LDS ----------------
__global__ __launch_bounds__(1024) void fused_decoder(
    const float* __restrict__ zbuf,
    const __hip_bfloat16* __restrict__ wb5, const float* __restrict__ b5,
    const __hip_bfloat16* __restrict__ wb6, const float* __restrict__ b6,
    const __hip_bfloat16* __restrict__ wb7, const float* __restrict__ b7,
    const __hip_bfloat16* __restrict__ wb8, const float* __restrict__ b8,
    const float* __restrict__ w9, const float* __restrict__ b9,
    float* __restrict__ dout)
{
  extern __shared__ __align__(16) char smem[];   // 30*4096 ring + 7168 red + 128 zl
  float* red = (float*)(smem + 122880);
  float* zl  = (float*)(smem + 130048);
  const int b = blockIdx.x;
  const int tid = threadIdx.x;

  if (tid < LSDIM) zl[tid] = zbuf[b * LSDIM + tid];
  // zero the two permanent halo slots (0 and 29); never written afterwards
  if (tid < 512) {
    const int s = (tid < 256) ? 0 : 29;
    short8 z8 = {0, 0, 0, 0, 0, 0, 0, 0};
    *(short8*)(smem + s * 4096 + (tid & 255) * 16) = z8;
  }
  __syncthreads();

  // synth conv5 input (ch0=row-grid, ch1=col-grid, ch2..31=z) into slots 1..28
  for (int idx = tid; idx < 28 * 32 * 4; idx += 1024) {
    const int icq = idx & 3;
    const int j = (idx >> 2) & 31;
    const int r = idx >> 7;
    const int gx = j - 1;
    short8 v = {0, 0, 0, 0, 0, 0, 0, 0};
    if ((unsigned)gx < 28u) {
      const float gyv = fmaf((float)r, 2.0f / 27.0f, -1.0f);
      const float gxv = fmaf((float)gx, 2.0f / 27.0f, -1.0f);
#pragma unroll
      for (int e = 0; e < 8; ++e) {
        int c = icq * 8 + e;
        float f = (c == 0) ? gyv : (c == 1) ? gxv : zl[c - 2];
        v[e] = __builtin_bit_cast(short, __float2bfloat16(f));
      }
    }
    int addr = (r + 1) * 4096 + j * 128 + icq * 16;
    addr ^= (j & 7) << 4;
    *(short8*)(smem + addr) = v;
  }
  // each conv_phase opens with __syncthreads(): synth/writes ordered before reads

  conv_phase<32, false>(smem, red, b, (const short8*)wb5, b5, nullptr, nullptr, nullptr);
  conv_phase<64, false>(smem, red, b, (const short8*)wb6, b6, nullptr, nullptr, nullptr);
  conv_phase<64, false>(smem, red, b, (const short8*)wb7, b7, nullptr, nullptr, nullptr);
  conv_phase<64, true >(smem, red, b, (const short8*)wb8, b8, w9, b9, dout);
}

extern "C" void kernel_launch(void* const* d_in, const int* in_sizes, int n_in,
                              void* d_out, int out_size, void* d_ws, size_t ws_size,
                              hipStream_t stream)
{
  const float* x   = (const float*)d_in[0];
  const float* eps = (const float*)d_in[1];
  const float* w1 = (const float*)d_in[2];  const float* b1 = (const float*)d_in[3];
  const float* w2 = (const float*)d_in[4];  const float* b2 = (const float*)d_in[5];
  const float* w3 = (const float*)d_in[6];  const float* b3 = (const float*)d_in[7];
  const float* w4 = (const float*)d_in[8];  const float* b4 = (const float*)d_in[9];
  const float* mw = (const float*)d_in[10]; const float* mb = (const float*)d_in[11];
  const float* vw = (const float*)d_in[12]; const float* vb = (const float*)d_in[13];
  const float* w5 = (const float*)d_in[14]; const float* b5 = (const float*)d_in[15];
  const float* w6 = (const float*)d_in[16]; const float* b6 = (const float*)d_in[17];
  const float* w7 = (const float*)d_in[18]; const float* b7 = (const float*)d_in[19];
  const float* w8 = (const float*)d_in[20]; const float* b8 = (const float*)d_in[21];
  const float* w9 = (const float*)d_in[22]; const float* b9 = (const float*)d_in[23];

  float* dout   = (float*)d_out;
  float* out_mu = dout + 802816;
  float* out_lv = dout + 833536;
  float* out_z  = dout + 864256;

  char* ws = (char*)d_ws;
  float* ws_z = (float*)ws;                                  // 122880 B
  __hip_bfloat16* wb5 = (__hip_bfloat16*)(ws + 122880);      // 36864 B
  __hip_bfloat16* wb6 = (__hip_bfloat16*)(ws + 159744);      // 73728 B
  __hip_bfloat16* wb7 = (__hip_bfloat16*)(ws + 233472);      // 73728 B
  __hip_bfloat16* wb8 = (__hip_bfloat16*)(ws + 307200);      // 73728 B

  const int smem_bytes = 130176;
  (void)hipFuncSetAttribute((const void*)fused_decoder,
                            hipFuncAttributeMaxDynamicSharedMemorySize, smem_bytes);

  repack_all<<<504, 256, 0, stream>>>(w5, w6, w7, w8, wb5, wb6, wb7, wb8);
  encoder_kernel<<<1024, 256, 0, stream>>>(x, eps, w1, b1, w2, b2, w3, b3, w4, b4,
                                           mw, mb, vw, vb, out_mu, out_lv, out_z, ws_z);
  fused_decoder<<<1024, 1024, smem_bytes, stream>>>(ws_z, wb5, b5, wb6, b6, wb7, b7,
                                                    wb8, b8, w9, b9, dout);
}

// Round 18
// 238.117 us; speedup vs baseline: 1.0337x; 1.0337x over previous
//
#include <hip/hip_runtime.h>
#include <hip/hip_bf16.h>

#define LSDIM 30

typedef __attribute__((ext_vector_type(8))) short short8;
typedef __attribute__((ext_vector_type(4))) short s16x4;
typedef __attribute__((ext_vector_type(4))) float f32x4;

__device__ __forceinline__ float lrelu(float v) { return v >= 0.0f ? v : 0.01f * v; }

// ---------------- Fused encoder: conv1..conv4 + FC + reparam ----------------
__global__ __launch_bounds__(256) void encoder_kernel(
    const float* __restrict__ x, const float* __restrict__ eps,
    const float* __restrict__ w1, const float* __restrict__ b1,
    const float* __restrict__ w2, const float* __restrict__ b2,
    const float* __restrict__ w3, const float* __restrict__ b3,
    const float* __restrict__ w4, const float* __restrict__ b4,
    const float* __restrict__ mw, const float* __restrict__ mb,
    const float* __restrict__ vw, const float* __restrict__ vb,
    float* __restrict__ out_mu, float* __restrict__ out_lv, float* __restrict__ out_z,
    float* __restrict__ ws_z)
{
  __shared__ float xs[784];
  __shared__ float h1[8 * 169];
  __shared__ float h2[16 * 36];
  __shared__ float h3[32 * 16];
  __shared__ float flat[256];
  __shared__ float mlv[60];

  const int b = blockIdx.x;
  const int tid = threadIdx.x;

  const float* xb = x + b * 784;
  for (int i = tid; i < 784; i += 256) xs[i] = xb[i];
  __syncthreads();

  for (int idx = tid; idx < 8 * 169; idx += 256) {
    int c = idx / 169, r = idx % 169;
    int py = r / 13, px = r % 13;
    float wv[9];
#pragma unroll
    for (int t = 0; t < 9; ++t) wv[t] = w1[c * 9 + t];
    float bias = b1[c];
    float m = -1e30f;
#pragma unroll
    for (int dy = 0; dy < 2; ++dy)
#pragma unroll
      for (int dx = 0; dx < 2; ++dx) {
        int oy = 2 * py + dy, ox = 2 * px + dx;
        float acc = bias;
#pragma unroll
        for (int ky = 0; ky < 3; ++ky)
#pragma unroll
          for (int kx = 0; kx < 3; ++kx)
            acc = fmaf(wv[ky * 3 + kx], xs[(oy + ky) * 28 + ox + kx], acc);
        m = fmaxf(m, lrelu(acc));
      }
    h1[idx] = m;
  }
  __syncthreads();

  for (int idx = tid; idx < 16 * 36; idx += 256) {
    int c = idx / 36, r = idx % 36;
    int py = r / 6, px = r % 6;
    float bias = b2[c];
    float m = -1e30f;
#pragma unroll
    for (int dy = 0; dy < 2; ++dy)
#pragma unroll
      for (int dx = 0; dx < 2; ++dx) {
        int oy = 2 * py + dy, ox = 2 * px + dx;
        float acc = bias;
        for (int ic = 0; ic < 8; ++ic) {
#pragma unroll
          for (int ky = 0; ky < 2; ++ky)
#pragma unroll
            for (int kx = 0; kx < 2; ++kx)
              acc = fmaf(w2[((c * 8 + ic) * 2 + ky) * 2 + kx],
                         h1[ic * 169 + (oy + ky) * 13 + ox + kx], acc);
        }
        m = fmaxf(m, lrelu(acc));
      }
    h2[idx] = m;
  }
  __syncthreads();

  for (int idx = tid; idx < 32 * 16; idx += 256) {
    int c = idx / 16, r = idx % 16;
    int y = r / 4, xq = r % 4;
    float acc = b3[c];
    for (int ic = 0; ic < 16; ++ic) {
#pragma unroll
      for (int ky = 0; ky < 3; ++ky)
#pragma unroll
        for (int kx = 0; kx < 3; ++kx)
          acc = fmaf(w3[((c * 16 + ic) * 3 + ky) * 3 + kx],
                     h2[ic * 36 + (y + ky) * 6 + xq + kx], acc);
    }
    h3[idx] = lrelu(acc);
  }
  __syncthreads();

  {
    int c = tid >> 2, r = tid & 3;
    int y = r >> 1, xq = r & 1;
    float acc = b4[c];
    for (int ic = 0; ic < 32; ++ic) {
#pragma unroll
      for (int ky = 0; ky < 3; ++ky)
#pragma unroll
        for (int kx = 0; kx < 3; ++kx)
          acc = fmaf(w4[((c * 32 + ic) * 3 + ky) * 3 + kx],
                     h3[ic * 16 + (y + ky) * 4 + xq + kx], acc);
    }
    flat[tid] = lrelu(acc);
  }
  __syncthreads();

  if (tid < 60) {
    int j = tid < 30 ? tid : tid - 30;
    const float* W = tid < 30 ? mw : vw;
    float acc = (tid < 30 ? mb[j] : vb[j]);
    for (int k = 0; k < 256; ++k) acc = fmaf(W[j * 256 + k], flat[k], acc);
    mlv[tid] = acc;
  }
  __syncthreads();

  if (tid < LSDIM) {
    float mu = mlv[tid], lv = mlv[30 + tid];
    float z = fmaf(eps[b * LSDIM + tid], expf(0.5f * lv), mu);
    out_mu[b * LSDIM + tid] = mu;
    out_lv[b * LSDIM + tid] = lv;
    out_z[b * LSDIM + tid] = z;
    ws_z[b * LSDIM + tid] = z;
  }
}

// ---------------- Weight repack ----------------
// wb[((nt*nks + ks)*64 + l)*8 + e] = W[k][n], k = ks*32 + ((l>>4)&3)*8 + e,
// n = nt*16 + (l&15), k = (dy*3+dx)*CIN + ic  (ks = dy*QK + q)
__global__ __launch_bounds__(256) void repack_all(
    const float* __restrict__ w5, const float* __restrict__ w6,
    const float* __restrict__ w7, const float* __restrict__ w8,
    __hip_bfloat16* __restrict__ wb5, __hip_bfloat16* __restrict__ wb6,
    __hip_bfloat16* __restrict__ wb7, __hip_bfloat16* __restrict__ wb8)
{
  int i = blockIdx.x * 256 + threadIdx.x;
  const float* w;
  __hip_bfloat16* wb;
  int CIN, nks, j;
  if (i < 18432)       { w = w5; wb = wb5; CIN = 32; nks = 9;  j = i; }
  else if (i < 55296)  { w = w6; wb = wb6; CIN = 64; nks = 18; j = i - 18432; }
  else if (i < 92160)  { w = w7; wb = wb7; CIN = 64; nks = 18; j = i - 55296; }
  else if (i < 129024) { w = w8; wb = wb8; CIN = 64; nks = 18; j = i - 92160; }
  else return;
  int e = j & 7, l = (j >> 3) & 63;
  int ksnt = j >> 9;
  int ks = ksnt % nks, nt = ksnt / nks;
  int k = ks * 32 + ((l >> 4) & 3) * 8 + e;
  int n = nt * 16 + (l & 15);
  int d = k / CIN, ic = k % CIN;
  int dy = d / 3, dx = d % 3;
  wb[j] = __float2bfloat16(w[((n * CIN + ic) * 3 + dy) * 3 + dx]);
}

// ---------------- One conv phase: 16 waves, 7-row slab, SWAPPED operands ----------------
// Static layout: row y at slot y+1; slots 0/29 permanent zero halos.
// addr = slot*4096 + j*128 + c*2, XOR ^= (j&7)<<4.
// 16 waves = 4 slabs (7 rows) x 2 nh (32-ch halves) x 2 mt (16-col halves).
// q SEQUENTIAL (#pragma unroll 1): the back-edge bounds B-load hoisting --
// full unroll hoists all 36 B frags and spills (R3-R9); ANY manual prefetch
// also spills (R15: arch budget pinned at 64 -- Bq 24 + A 8 + bias/addr ~30
// fills it exactly). Lockstep q-order is deliberately kept: same-nh waves
// fetch the SAME wb lines simultaneously -> L2 broadcast (R17's stagger
// de-correlated them, -3%). setprio was null (R16). This is the measured
// optimum of this structure (R14: 207us decoder, MfmaUtil 51%).
// mfma(W, X, acc): swap transposes D so each lane holds 4 CONSECUTIVE
// CHANNELS at one column -> b64 epilogue writes (R14: 250->207 us).
template <int CIN, bool FUSE9>
__device__ __forceinline__ void conv_phase(
    char* __restrict__ smem, float* __restrict__ red, int b,
    const short8* __restrict__ wbp, const float* __restrict__ bias,
    const float* __restrict__ w9, const float* __restrict__ b9,
    float* __restrict__ dout)
{
  constexpr int NKS = CIN * 9 / 32;   // 9 or 18
  constexpr int QK  = NKS / 3;        // per-dy k-steps: 3 or 6

  const int tid = threadIdx.x;
  const int lane = tid & 63, wv = tid >> 6;     // wv 0..15
  const int slab = wv >> 2;                     // 0..3
  const int nh   = (wv >> 1) & 1;               // channel half
  const int mt   = wv & 1;                      // column half
  const int lg = (lane >> 4) & 3, ml = lane & 15;

  // per-lane bias vectors: 4 consecutive channels per tt
  f32x4 bbv[2];
#pragma unroll
  for (int tt = 0; tt < 2; ++tt)
    bbv[tt] = *(const f32x4*)(bias + (2 * nh + tt) * 16 + lg * 4);

  f32x4 acc[7][2];   // [o][tt]; lane holds channels n0..n0+3 at col xx
#pragma unroll
  for (int o = 0; o < 7; ++o)
#pragma unroll
    for (int nt = 0; nt < 2; ++nt) {
      f32x4 z = {0.f, 0.f, 0.f, 0.f};
      acc[o][nt] = z;
    }

  __syncthreads();   // previous phase's writes (or synth) visible

#pragma unroll 1     // REAL loop: bounds B-load hoisting to ~1 iteration
  for (int q = 0; q < QK; ++q) {
    short8 Bq[3][2];  // weight fragments: 3 dy x 2 nt = 24 VGPRs
#pragma unroll
    for (int dy = 0; dy < 3; ++dy)
#pragma unroll
      for (int nt = 0; nt < 2; ++nt)
        Bq[dy][nt] = wbp[((2 * nh + nt) * NKS + dy * QK + q) * 64 + lane];

    const int dx  = (CIN == 64) ? (q >> 1) : q;
    const int ic0 = ((CIN == 64) ? ((q & 1) * 32) : 0) + lg * 8;
    const int j   = (mt * 16 + ml + dx) & 31;   // wrapped lanes feed x>=28 (discarded)
    const int off = (j * 128 + ic0 * 2) ^ ((j & 7) << 4);

#pragma unroll
    for (int r = 0; r < 9; ++r) {    // input rows 7*slab-1 .. 7*slab+7
      short8 A = *(const short8*)(smem + (7 * slab + r) * 4096 + off);
#pragma unroll
      for (int dy = 0; dy < 3; ++dy) {
        const int o = r - dy;        // output row within slab
        if (o < 0 || o > 6) continue;
        // SWAPPED: weights in A-slot, acts in B-slot
        acc[o][0] = __builtin_amdgcn_mfma_f32_16x16x32_bf16(Bq[dy][0], A, acc[o][0], 0, 0, 0);
        acc[o][1] = __builtin_amdgcn_mfma_f32_16x16x32_bf16(Bq[dy][1], A, acc[o][1], 0, 0, 0);
      }
    }
  }

  __syncthreads();   // ALL reads of this conv done -> in-place writes safe

  const int xx = mt * 16 + ml;   // this lane's output column (fixed)

  if constexpr (!FUSE9) {
    if (xx < 28) {
      const int j = xx + 1;
#pragma unroll
      for (int o = 0; o < 7; ++o) {
        const int wslot = 7 * slab + o + 1;
#pragma unroll
        for (int tt = 0; tt < 2; ++tt) {
          const int n0 = (2 * nh + tt) * 16 + lg * 4;
          s16x4 pk;
#pragma unroll
          for (int reg = 0; reg < 4; ++reg) {
            __hip_bfloat16 h = __float2bfloat16(lrelu(acc[o][tt][reg] + bbv[tt][reg]));
            pk[reg] = __builtin_bit_cast(short, h);
          }
          int addr = wslot * 4096 + j * 128 + n0 * 2;
          addr ^= (j & 7) << 4;
          *(s16x4*)(smem + addr) = pk;   // 8B: 4 consecutive channels
        }
      }
    }
    // re-zero x-pad cols 0 and 29 of written rows (b64 chunks, ml 0/1 lanes)
    if (mt == 0 && ml < 2) {
      const int j = ml ? 29 : 0;
      s16x4 z4 = {0, 0, 0, 0};
#pragma unroll
      for (int o = 0; o < 7; ++o) {
        const int wslot = 7 * slab + o + 1;
#pragma unroll
        for (int tt = 0; tt < 2; ++tt) {
          const int n0 = (2 * nh + tt) * 16 + lg * 4;
          int addr = wslot * 4096 + j * 128 + n0 * 2;
          addr ^= (j & 7) << 4;
          *(s16x4*)(smem + addr) = z4;
        }
      }
    }
    // next phase's opening barrier orders these writes before its reads
  } else {
    // conv9 (1x1, 64->1): lane holds 8 channels (2tt x 4reg) at col xx;
    // in-lane dot, then reduce across lg groups (shfl 16, 32) = 32-ch sum.
    f32x4 w9v[2];
#pragma unroll
    for (int tt = 0; tt < 2; ++tt)
      w9v[tt] = *(const f32x4*)(w9 + (2 * nh + tt) * 16 + lg * 4);
    const float b9v = b9[0];
#pragma unroll
    for (int o = 0; o < 7; ++o) {
      float p = 0.0f;
#pragma unroll
      for (int tt = 0; tt < 2; ++tt)
#pragma unroll
        for (int reg = 0; reg < 4; ++reg)
          p = fmaf(w9v[tt][reg], lrelu(acc[o][tt][reg] + bbv[tt][reg]), p);
      p += __shfl_xor(p, 16);
      p += __shfl_xor(p, 32);
      if (lg == 0 && xx < 28) {
        const int y = 7 * slab + o;
        red[(y * 32 + xx) * 2 + nh] = p;
      }
    }
    __syncthreads();
    for (int idx = tid; idx < 784; idx += 1024) {
      const int y = idx / 28, xc = idx % 28;
      float o9 = lrelu(b9v + red[(y * 32 + xc) * 2] + red[(y * 32 + xc) * 2 + 1]);
      dout[b * 784 + y * 28 + xc] = o9;
    }
  }
}

// ---------------- Fused decoder: synth + conv5..conv8 + conv9, all in LDS ----------------
__global__ __launch_bounds__(1024) void fused_decoder(
    const float* __restrict__ zbuf,
    const __hip_bfloat16* __restrict__ wb5, const float* __restrict__ b5,
    const __hip_bfloat16* __restrict__ wb6, const float* __restrict__ b6,
    const __hip_bfloat16* __restrict__ wb7, const float* __restrict__ b7,
    const __hip_bfloat16* __restrict__ wb8, const float* __restrict__ b8,
    const float* __restrict__ w9, const float* __restrict__ b9,
    float* __restrict__ dout)
{
  extern __shared__ __align__(16) char smem[];   // 30*4096 ring + 7168 red + 128 zl
  float* red = (float*)(smem + 122880);
  float* zl  = (float*)(smem + 130048);
  const int b = blockIdx.x;
  const int tid = threadIdx.x;

  if (tid < LSDIM) zl[tid] = zbuf[b * LSDIM + tid];
  // zero the two permanent halo slots (0 and 29); never written afterwards
  if (tid < 512) {
    const int s = (tid < 256) ? 0 : 29;
    short8 z8 = {0, 0, 0, 0, 0, 0, 0, 0};
    *(short8*)(smem + s * 4096 + (tid & 255) * 16) = z8;
  }
  __syncthreads();

  // synth conv5 input (ch0=row-grid, ch1=col-grid, ch2..31=z) into slots 1..28
  for (int idx = tid; idx < 28 * 32 * 4; idx += 1024) {
    const int icq = idx & 3;
    const int j = (idx >> 2) & 31;
    const int r = idx >> 7;
    const int gx = j - 1;
    short8 v = {0, 0, 0, 0, 0, 0, 0, 0};
    if ((unsigned)gx < 28u) {
      const float gyv = fmaf((float)r, 2.0f / 27.0f, -1.0f);
      const float gxv = fmaf((float)gx, 2.0f / 27.0f, -1.0f);
#pragma unroll
      for (int e = 0; e < 8; ++e) {
        int c = icq * 8 + e;
        float f = (c == 0) ? gyv : (c == 1) ? gxv : zl[c - 2];
        v[e] = __builtin_bit_cast(short, __float2bfloat16(f));
      }
    }
    int addr = (r + 1) * 4096 + j * 128 + icq * 16;
    addr ^= (j & 7) << 4;
    *(short8*)(smem + addr) = v;
  }
  // each conv_phase opens with __syncthreads(): synth/writes ordered before reads

  conv_phase<32, false>(smem, red, b, (const short8*)wb5, b5, nullptr, nullptr, nullptr);
  conv_phase<64, false>(smem, red, b, (const short8*)wb6, b6, nullptr, nullptr, nullptr);
  conv_phase<64, false>(smem, red, b, (const short8*)wb7, b7, nullptr, nullptr, nullptr);
  conv_phase<64, true >(smem, red, b, (const short8*)wb8, b8, w9, b9, dout);
}

extern "C" void kernel_launch(void* const* d_in, const int* in_sizes, int n_in,
                              void* d_out, int out_size, void* d_ws, size_t ws_size,
                              hipStream_t stream)
{
  const float* x   = (const float*)d_in[0];
  const float* eps = (const float*)d_in[1];
  const float* w1 = (const float*)d_in[2];  const float* b1 = (const float*)d_in[3];
  const float* w2 = (const float*)d_in[4];  const float* b2 = (const float*)d_in[5];
  const float* w3 = (const float*)d_in[6];  const float* b3 = (const float*)d_in[7];
  const float* w4 = (const float*)d_in[8];  const float* b4 = (const float*)d_in[9];
  const float* mw = (const float*)d_in[10]; const float* mb = (const float*)d_in[11];
  const float* vw = (const float*)d_in[12]; const float* vb = (const float*)d_in[13];
  const float* w5 = (const float*)d_in[14]; const float* b5 = (const float*)d_in[15];
  const float* w6 = (const float*)d_in[16]; const float* b6 = (const float*)d_in[17];
  const float* w7 = (const float*)d_in[18]; const float* b7 = (const float*)d_in[19];
  const float* w8 = (const float*)d_in[20]; const float* b8 = (const float*)d_in[21];
  const float* w9 = (const float*)d_in[22]; const float* b9 = (const float*)d_in[23];

  float* dout   = (float*)d_out;
  float* out_mu = dout + 802816;
  float* out_lv = dout + 833536;
  float* out_z  = dout + 864256;

  char* ws = (char*)d_ws;
  float* ws_z = (float*)ws;                                  // 122880 B
  __hip_bfloat16* wb5 = (__hip_bfloat16*)(ws + 122880);      // 36864 B
  __hip_bfloat16* wb6 = (__hip_bfloat16*)(ws + 159744);      // 73728 B
  __hip_bfloat16* wb7 = (__hip_bfloat16*)(ws + 233472);      // 73728 B
  __hip_bfloat16* wb8 = (__hip_bfloat16*)(ws + 307200);      // 73728 B

  const int smem_bytes = 130176;
  (void)hipFuncSetAttribute((const void*)fused_decoder,
                            hipFuncAttributeMaxDynamicSharedMemorySize, smem_bytes);

  repack_all<<<504, 256, 0, stream>>>(w5, w6, w7, w8, wb5, wb6, wb7, wb8);
  encoder_kernel<<<1024, 256, 0, stream>>>(x, eps, w1, b1, w2, b2, w3, b3, w4, b4,
                                           mw, mb, vw, vb, out_mu, out_lv, out_z, ws_z);
  fused_decoder<<<1024, 1024, smem_bytes, stream>>>(ws_z, wb5, b5, wb6, b6, wb7, b7,
                                                    wb8, b8, w9, b9, dout);
}